// Round 4
// baseline (354.132 us; speedup 1.0000x reference)
//
#include <hip/hip_runtime.h>
#include <hip/hip_bf16.h>

typedef __bf16 bf16x8 __attribute__((ext_vector_type(8)));
typedef __bf16 bf16x4 __attribute__((ext_vector_type(4)));
typedef float floatx4 __attribute__((ext_vector_type(4)));

#define LDW 136  // activation row stride (272B, 16B-aligned rows)
#define PXW 40   // pre_msg/x row stride (80B, 16B-aligned, odd dword stride -> no conflicts)

// ws layout (bf16 element offsets). Wt[n][k] = W[k][n] for 128-col weights.
#define O_E1W2  0
#define O_E2W1  16384
#define O_E2W2  49152
#define O_E3W1  65536
#define O_E3W2  81920
#define O_E4W1  98304
#define O_E4W2  131072
#define O_DM2T0 147456
#define O_DM2T1 163840
#define O_DO1   180224
#define O_DO2   196608
#define O_EWOUT 212992   // [16][128]: rows 0,1 = ew_out^T, rest 0
#define O_DW3   215040   // [16][128]: rows 0..2 = d_out_w3^T, rest 0
#define O_E1W1P 217088   // [128][32]: cols 3..5 = e1w1^T (k maps to pxb send slot)
#define O_M1T0P 221184   // [128][32]: cols 0..5 = d_msg_w1[0]^T
#define O_M1T1P 225280   // [128][32]: cols 0..5 = d_msg_w1[1]^T
#define O_DO1XP 229376   // [128][32]: cols 3..5 = d_out_w1 rows 0..2 ^T
#define WS_ELEMS 233472

__global__ void prep_kernel(const float* e1w2, const float* e2w1, const float* e2w2,
    const float* e3w1, const float* e3w2, const float* e4w1, const float* e4w2,
    const float* dmsg2, const float* dout1, const float* dout2,
    const float* ew_out, const float* dout_w3, const float* e1w1,
    const float* dmsg_w1, __hip_bfloat16* ws) {
  int idx = blockIdx.x * 256 + threadIdx.x;
  if (idx >= WS_ELEMS) return;
  float v;
  if (idx < O_E2W1)      { int l = idx;           v = e1w2[(l & 127) * 128 + (l >> 7)]; }
  else if (idx < O_E2W2) { int l = idx - O_E2W1;  v = e2w1[(l & 255) * 128 + (l >> 8)]; }
  else if (idx < O_E3W1) { int l = idx - O_E2W2;  v = e2w2[(l & 127) * 128 + (l >> 7)]; }
  else if (idx < O_E3W2) { int l = idx - O_E3W1;  v = e3w1[(l & 127) * 128 + (l >> 7)]; }
  else if (idx < O_E4W1) { int l = idx - O_E3W2;  v = e3w2[(l & 127) * 128 + (l >> 7)]; }
  else if (idx < O_E4W2) { int l = idx - O_E4W1;  v = e4w1[(l & 255) * 128 + (l >> 8)]; }
  else if (idx < O_DM2T0){ int l = idx - O_E4W2;  v = e4w2[(l & 127) * 128 + (l >> 7)]; }
  else if (idx < O_DM2T1){ int l = idx - O_DM2T0; v = dmsg2[(l & 127) * 128 + (l >> 7)]; }
  else if (idx < O_DO1)  { int l = idx - O_DM2T1; v = dmsg2[16384 + (l & 127) * 128 + (l >> 7)]; }
  else if (idx < O_DO2)  { int l = idx - O_DO1;   v = dout1[384 + (l & 127) * 128 + (l >> 7)]; }
  else if (idx < O_EWOUT){ int l = idx - O_DO2;   v = dout2[(l & 127) * 128 + (l >> 7)]; }
  else if (idx < O_DW3)  { int l = idx - O_EWOUT; int n = l >> 7;
                           v = (n < 2) ? ew_out[(l & 127) * 2 + n] : 0.f; }
  else if (idx < O_E1W1P){ int l = idx - O_DW3;   int n = l >> 7;
                           v = (n < 3) ? dout_w3[(l & 127) * 3 + n] : 0.f; }
  else if (idx < O_M1T0P){ int l = idx - O_E1W1P; int n = l >> 5, c = l & 31;
                           v = (c >= 3 && c < 6) ? e1w1[(c - 3) * 128 + n] : 0.f; }
  else if (idx < O_M1T1P){ int l = idx - O_M1T0P; int n = l >> 5, c = l & 31;
                           v = (c < 6) ? dmsg_w1[c * 128 + n] : 0.f; }
  else if (idx < O_DO1XP){ int l = idx - O_M1T1P; int n = l >> 5, c = l & 31;
                           v = (c < 6) ? dmsg_w1[768 + c * 128 + n] : 0.f; }
  else                   { int l = idx - O_DO1XP; int n = l >> 5, c = l & 31;
                           v = (c >= 3 && c < 6) ? dout1[(c - 3) * 128 + n] : 0.f; }
  ws[idx] = __float2bfloat16(v);
}

union PK { bf16x4 v; __hip_bfloat16 h[4]; };

__global__ __launch_bounds__(256, 3) void nri_fused(
    const float* __restrict__ x,
    const float* __restrict__ e1b1, const float* __restrict__ e1b2,
    const float* __restrict__ e2b1, const float* __restrict__ e2b2,
    const float* __restrict__ e3b1, const float* __restrict__ e3b2,
    const float* __restrict__ e4b1, const float* __restrict__ e4b2,
    const float* __restrict__ eb_out,
    const float* __restrict__ dmsg_b1, const float* __restrict__ dmsg_b2,
    const float* __restrict__ dout_b1, const float* __restrict__ dout_b2,
    const float* __restrict__ dout_b3,
    const __bf16* __restrict__ wt, float* __restrict__ out)
{
  const int tid  = threadIdx.x;
  const int wave = tid >> 6;
  const int lane = tid & 63;
  const int nl   = lane & 15;
  const int quad = lane >> 4;
  const int gx   = blockIdx.x * 144;  // 8 graphs -> 48 rows

  __shared__ __align__(16) __hip_bfloat16 bufA[48 * LDW];
  __shared__ __align__(16) __hip_bfloat16 bufB[48 * LDW];
  __shared__ __align__(16) __hip_bfloat16 bufC[48 * LDW];
  __shared__ __align__(16) __hip_bfloat16 pxb[48 * PXW];  // [recv x(3) | send x(3) | 0...]
  __shared__ float xs[144];
  __shared__ float rtw[96];
  __shared__ __align__(16) float biasL[15 * 128];
  __shared__ float obuf[144];

  // ---- stage 0 ----
  if (tid < 144) xs[tid] = x[gx + tid];
  for (int i = tid; i < 1920; i += 256) {
    int row = i >> 7, c = i & 127;
    float v;
    if (row == 0) v = e1b1[c]; else if (row == 1) v = e1b2[c];
    else if (row == 2) v = e2b1[c]; else if (row == 3) v = e2b2[c];
    else if (row == 4) v = e3b1[c]; else if (row == 5) v = e3b2[c];
    else if (row == 6) v = e4b1[c]; else if (row == 7) v = e4b2[c];
    else if (row == 8) v = dmsg_b1[c]; else if (row == 9) v = dmsg_b1[128 + c];
    else if (row == 10) v = dmsg_b2[c]; else if (row == 11) v = dmsg_b2[128 + c];
    else if (row == 12) v = dout_b1[c]; else if (row == 13) v = dout_b2[c];
    else v = (c < 2) ? eb_out[c] : ((c >= 4 && c < 7) ? dout_b3[c - 4] : 0.f);
    biasL[i] = v;
  }
  for (int i = tid; i < 48 * PXW; i += 256) {
    int row = i / PXW, c = i - row * PXW;
    int e = row % 6;
    float v = 0.f;
    if (c < 3)      { int rr = row + ((e == 5) ? -5 : 1); v = x[gx + rr * 3 + c]; }
    else if (c < 6) v = x[gx + row * 3 + (c - 3)];
    pxb[i] = __float2bfloat16(v);
  }
  __syncthreads();

  // ---- swapped-operand helpers: A=weights(n-slice), B=activations(rows), D[n][row] ----
  auto initS = [&](floatx4 (&acc)[2][3], int brow) {
#pragma unroll
    for (int mt = 0; mt < 2; ++mt) {
      floatx4 bv = *(const floatx4*)(biasL + brow * 128 + wave * 32 + mt * 16 + quad * 4);
#pragma unroll
      for (int rt = 0; rt < 3; ++rt) acc[mt][rt] = bv;
    }
  };

  auto gemmS128 = [&](floatx4 (&acc)[2][3], const __bf16* wA, const __hip_bfloat16* act) {
    const __bf16* ab  = (const __bf16*)(const void*)act;
    const __bf16* a0p = wA + (wave * 32 + nl) * 128 + quad * 8;
    const __bf16* a1p = a0p + 16 * 128;
#pragma unroll
    for (int ks = 0; ks < 4; ++ks) {
      bf16x8 a0 = *(const bf16x8*)(a0p + ks * 32);
      bf16x8 a1 = *(const bf16x8*)(a1p + ks * 32);
#pragma unroll
      for (int rt = 0; rt < 3; ++rt) {
        bf16x8 b = *(const bf16x8*)(ab + (rt * 16 + nl) * LDW + ks * 32 + quad * 8);
        acc[0][rt] = __builtin_amdgcn_mfma_f32_16x16x32_bf16(a0, b, acc[0][rt], 0, 0, 0);
        acc[1][rt] = __builtin_amdgcn_mfma_f32_16x16x32_bf16(a1, b, acc[1][rt], 0, 0, 0);
      }
    }
  };

  auto gemmS256 = [&](floatx4 (&acc)[2][3], const __bf16* wA,
                      const __hip_bfloat16* act0, bool recv0, const __hip_bfloat16* act1) {
    int rof0[3], rof1[3];
#pragma unroll
    for (int rt = 0; rt < 3; ++rt) {
      int r = rt * 16 + nl;
      rof1[rt] = r * LDW;
      if (recv0) { int e = r % 6; r += (e == 5) ? -5 : 1; }
      rof0[rt] = r * LDW;
    }
    const __bf16* ab0 = (const __bf16*)(const void*)act0;
    const __bf16* ab1 = (const __bf16*)(const void*)act1;
    const __bf16* a0p = wA + (wave * 32 + nl) * 256 + quad * 8;
    const __bf16* a1p = a0p + 16 * 256;
#pragma unroll
    for (int ks = 0; ks < 8; ++ks) {
      bf16x8 a0 = *(const bf16x8*)(a0p + ks * 32);
      bf16x8 a1 = *(const bf16x8*)(a1p + ks * 32);
      const __bf16* ab = (ks < 4) ? ab0 : ab1;
      const int* rof   = (ks < 4) ? rof0 : rof1;
      int kk = (ks & 3) * 32 + quad * 8;
#pragma unroll
      for (int rt = 0; rt < 3; ++rt) {
        bf16x8 b = *(const bf16x8*)(ab + rof[rt] + kk);
        acc[0][rt] = __builtin_amdgcn_mfma_f32_16x16x32_bf16(a0, b, acc[0][rt], 0, 0, 0);
        acc[1][rt] = __builtin_amdgcn_mfma_f32_16x16x32_bf16(a1, b, acc[1][rt], 0, 0, 0);
      }
    }
  };

  // K=32 zero-padded GEMM against pxb
  auto gemmS32 = [&](floatx4 (&acc)[2][3], const __bf16* wAp) {
    const __bf16* pb = (const __bf16*)(const void*)pxb;
    bf16x8 a0 = *(const bf16x8*)(wAp + (wave * 32 + nl) * 32 + quad * 8);
    bf16x8 a1 = *(const bf16x8*)(wAp + (wave * 32 + 16 + nl) * 32 + quad * 8);
#pragma unroll
    for (int rt = 0; rt < 3; ++rt) {
      bf16x8 b = *(const bf16x8*)(pb + (rt * 16 + nl) * PXW + quad * 8);
      acc[0][rt] = __builtin_amdgcn_mfma_f32_16x16x32_bf16(a0, b, acc[0][rt], 0, 0, 0);
      acc[1][rt] = __builtin_amdgcn_mfma_f32_16x16x32_bf16(a1, b, acc[1][rt], 0, 0, 0);
    }
  };

  // act: 1=ELU 2=ReLU; packed b64 writes (bank-balanced)
  auto storeS = [&](floatx4 (&acc)[2][3], int act, __hip_bfloat16* ob) {
#pragma unroll
    for (int mt = 0; mt < 2; ++mt)
#pragma unroll
      for (int rt = 0; rt < 3; ++rt) {
        int row = rt * 16 + nl;
        PK p;
#pragma unroll
        for (int r = 0; r < 4; ++r) {
          float z = acc[mt][rt][r];
          if (act == 1) z = (z > 0.f) ? z : (__expf(z) - 1.f);
          else z = fmaxf(z, 0.f);
          p.h[r] = __float2bfloat16(z);
        }
        *(bf16x4*)((__bf16*)(void*)ob + row * LDW + wave * 32 + mt * 16 + quad * 4) = p.v;
      }
  };

  floatx4 acc[2][3];

  // s1: hh = ELU(e1w1^T(pad) (x) pxb) -> bufA
  initS(acc, 0); gemmS32(acc, wt + O_E1W1P); storeS(acc, 1, bufA);
  __syncthreads();
  // s2: h = ELU(e1w2 (x) bufA) -> bufB
  initS(acc, 1); gemmS128(acc, wt + O_E1W2, bufA); storeS(acc, 1, bufB);
  __syncthreads();
  // s3: ELU(e2w1 (x) [h_recv | h]) -> bufA
  initS(acc, 2); gemmS256(acc, wt + O_E2W1, bufB, true, bufB); storeS(acc, 1, bufA);
  __syncthreads();
  // s4: he = ELU(e2w2 (x) bufA) -> bufC (keep)
  initS(acc, 3); gemmS128(acc, wt + O_E2W2, bufA); storeS(acc, 1, bufC);
  __syncthreads();
  // s5: ELU(e3w1 (x) he) -> bufA
  initS(acc, 4); gemmS128(acc, wt + O_E3W1, bufC); storeS(acc, 1, bufA);
  __syncthreads();
  // s6: h2 = ELU(e3w2 (x) bufA) -> bufB
  initS(acc, 5); gemmS128(acc, wt + O_E3W2, bufA); storeS(acc, 1, bufB);
  __syncthreads();
  // s7: ELU(e4w1 (x) [h2 | he]) -> bufA
  initS(acc, 6); gemmS256(acc, wt + O_E4W1, bufB, false, bufC); storeS(acc, 1, bufA);
  __syncthreads();
  // s8: h3 = ELU(e4w2 (x) bufA) -> bufB
  initS(acc, 7); gemmS128(acc, wt + O_E4W2, bufA); storeS(acc, 1, bufB);
  __syncthreads();

  // s9: logits + softmax (waves 0..2; wave 3 falls through to s10)
  if (wave < 3) {
    floatx4 lg = {0.f, 0.f, 0.f, 0.f};
    const __bf16* ab = (const __bf16*)(const void*)bufB;
    const __bf16* ap = wt + O_EWOUT + nl * 128 + quad * 8;
#pragma unroll
    for (int ks = 0; ks < 4; ++ks) {
      bf16x8 a = *(const bf16x8*)(ap + ks * 32);
      bf16x8 b = *(const bf16x8*)(ab + (wave * 16 + nl) * LDW + ks * 32 + quad * 8);
      lg = __builtin_amdgcn_mfma_f32_16x16x32_bf16(a, b, lg, 0, 0, 0);
    }
    if (quad == 0) {
      int row = wave * 16 + nl;
      float l0 = lg[0] + biasL[14 * 128 + 0];
      float l1 = lg[1] + biasL[14 * 128 + 1];
      float mx = fmaxf(l0, l1);
      float ea = __expf(l0 - mx), eb = __expf(l1 - mx);
      float inv = 1.f / (ea + eb);
      rtw[row * 2] = ea * inv; rtw[row * 2 + 1] = eb * inv;
    }
  }
  // s10: m1 for both edge types (K=32 pad): t0 -> bufA, t1 -> bufC
  floatx4 acc1[2][3];
  initS(acc, 8);  gemmS32(acc, wt + O_M1T0P);  storeS(acc, 2, bufA);
  initS(acc1, 9); gemmS32(acc1, wt + O_M1T1P); storeS(acc1, 2, bufC);
  __syncthreads();

  // s11: msg = rt0*relu(dm2t0 (x) m1t0) + rt1*relu(...t1); edge->node remap -> bufB
  initS(acc, 10);  gemmS128(acc, wt + O_DM2T0, bufA);
  initS(acc1, 11); gemmS128(acc1, wt + O_DM2T1, bufC);
#pragma unroll
  for (int mt = 0; mt < 2; ++mt)
#pragma unroll
    for (int rt = 0; rt < 3; ++rt) {
      int row = rt * 16 + nl;
      float r0 = rtw[row * 2], r1 = rtw[row * 2 + 1];
      int e = row % 6;
      int orow = row + ((e == 5) ? -5 : 1);
      PK p;
#pragma unroll
      for (int r = 0; r < 4; ++r) {
        float z = r0 * fmaxf(acc[mt][rt][r], 0.f) + r1 * fmaxf(acc1[mt][rt][r], 0.f);
        p.h[r] = __float2bfloat16(z);
      }
      *(bf16x4*)((__bf16*)(void*)bufB + orow * LDW + wave * 32 + mt * 16 + quad * 4) = p.v;
    }
  __syncthreads();

  // s12: p1 = relu(do1 (x) agg + do1x(pad) (x) pxb) -> bufA
  initS(acc, 12); gemmS128(acc, wt + O_DO1, bufB); gemmS32(acc, wt + O_DO1XP);
  storeS(acc, 2, bufA);
  __syncthreads();
  // s13: p2 = relu(do2 (x) bufA) -> bufC
  initS(acc, 13); gemmS128(acc, wt + O_DO2, bufA); storeS(acc, 2, bufC);
  __syncthreads();

  // s14: out = x + dw3^T (x) p2 + b3
  if (wave < 3) {
    floatx4 d = {0.f, 0.f, 0.f, 0.f};
    const __bf16* ab = (const __bf16*)(const void*)bufC;
    const __bf16* ap = wt + O_DW3 + nl * 128 + quad * 8;
#pragma unroll
    for (int ks = 0; ks < 4; ++ks) {
      bf16x8 a = *(const bf16x8*)(ap + ks * 32);
      bf16x8 b = *(const bf16x8*)(ab + (wave * 16 + nl) * LDW + ks * 32 + quad * 8);
      d = __builtin_amdgcn_mfma_f32_16x16x32_bf16(a, b, d, 0, 0, 0);
    }
    if (quad == 0) {
      int row = wave * 16 + nl;
#pragma unroll
      for (int r = 0; r < 3; ++r)
        obuf[row * 3 + r] = xs[row * 3 + r] + d[r] + biasL[14 * 128 + 4 + r];
    }
  }
  __syncthreads();
  if (tid < 144) out[gx + tid] = obuf[tid];
}

extern "C" void kernel_launch(void* const* d_in, const int* in_sizes, int n_in,
                              void* d_out, int out_size, void* d_ws, size_t ws_size,
                              hipStream_t stream) {
  const float* x       = (const float*)d_in[0];
  const float* e1w1    = (const float*)d_in[3];
  const float* e1b1    = (const float*)d_in[4];
  const float* e1w2    = (const float*)d_in[5];
  const float* e1b2    = (const float*)d_in[6];
  const float* e2w1    = (const float*)d_in[7];
  const float* e2b1    = (const float*)d_in[8];
  const float* e2w2    = (const float*)d_in[9];
  const float* e2b2    = (const float*)d_in[10];
  const float* e3w1    = (const float*)d_in[11];
  const float* e3b1    = (const float*)d_in[12];
  const float* e3w2    = (const float*)d_in[13];
  const float* e3b2    = (const float*)d_in[14];
  const float* e4w1    = (const float*)d_in[15];
  const float* e4b1    = (const float*)d_in[16];
  const float* e4w2    = (const float*)d_in[17];
  const float* e4b2    = (const float*)d_in[18];
  const float* ew_out  = (const float*)d_in[19];
  const float* eb_out  = (const float*)d_in[20];
  const float* dmsg_w1 = (const float*)d_in[21];
  const float* dmsg_b1 = (const float*)d_in[22];
  const float* dmsg_w2 = (const float*)d_in[23];
  const float* dmsg_b2 = (const float*)d_in[24];
  const float* dout_w1 = (const float*)d_in[25];
  const float* dout_b1 = (const float*)d_in[26];
  const float* dout_w2 = (const float*)d_in[27];
  const float* dout_b2 = (const float*)d_in[28];
  const float* dout_w3 = (const float*)d_in[29];
  const float* dout_b3 = (const float*)d_in[30];

  prep_kernel<<<(WS_ELEMS + 255) / 256, 256, 0, stream>>>(
      e1w2, e2w1, e2w2, e3w1, e3w2, e4w1, e4w2, dmsg_w2, dout_w1, dout_w2,
      ew_out, dout_w3, e1w1, dmsg_w1, (__hip_bfloat16*)d_ws);

  nri_fused<<<32768 / 8, 256, 0, stream>>>(
      x, e1b1, e1b2, e2b1, e2b2, e3b1, e3b2, e4b1, e4b2, eb_out,
      dmsg_b1, dmsg_b2, dout_b1, dout_b2, dout_b3,
      (const __bf16*)d_ws, (float*)d_out);
}